// Round 6
// baseline (245.461 us; speedup 1.0000x reference)
//
#include <hip/hip_runtime.h>
#include <hip/hip_bf16.h>

#define NSEQ 4096
#define FT 256
#define BK 64

typedef __attribute__((ext_vector_type(8))) short bf16x8;
typedef __attribute__((ext_vector_type(4))) float f32x4;

__device__ __forceinline__ ushort f2bf(float f) {
  __hip_bfloat16 h = __float2bfloat16(f);
  return *reinterpret_cast<const ushort*>(&h);
}

// XOR swizzle of 16B granules within a 128B row (kernel A only).
__device__ __forceinline__ int swz(int row, int byteInRow) {
  return row * 128 + (byteInRow ^ ((row & 7) << 4));
}

__device__ __forceinline__ void mma_step(const char* lAp, const char* lBp,
                                         int lane, int wm, int wn,
                                         f32x4 acc[2][4]) {
  const int r16 = lane & 15;
  const int g16 = (lane >> 4) * 16;
#pragma unroll
  for (int kk = 0; kk < 2; ++kk) {
    const int kb = kk * 64 + g16;
    bf16x8 a[2], b[4];
#pragma unroll
    for (int mi = 0; mi < 2; ++mi) {
      const int row = wm * 32 + mi * 16 + r16;
      a[mi] = *reinterpret_cast<const bf16x8*>(lAp + swz(row, kb));
    }
#pragma unroll
    for (int ni = 0; ni < 4; ++ni) {
      const int row = wn * 64 + ni * 16 + r16;
      b[ni] = *reinterpret_cast<const bf16x8*>(lBp + swz(row, kb));
    }
#pragma unroll
    for (int mi = 0; mi < 2; ++mi)
#pragma unroll
      for (int ni = 0; ni < 4; ++ni)
        acc[mi][ni] = __builtin_amdgcn_mfma_f32_16x16x32_bf16(a[mi], b[ni],
                                                             acc[mi][ni], 0, 0, 0);
  }
}

// ---------------- Kernel A: hT[b][o][n] = (seq @ W^T + b) as bf16 ----------------
__global__ __launch_bounds__(512) void linear_kernel(
    const float* __restrict__ seq, const float* __restrict__ W,
    const float* __restrict__ bias, ushort* __restrict__ hT) {
  __shared__ __align__(16) ushort lA[2][64 * 64];
  __shared__ __align__(16) ushort lB[2][256 * 64];

  const int tid = threadIdx.x;
  const int lane = tid & 63;
  const int wid = tid >> 6;
  const int wm = wid >> 2, wn = wid & 3;
  const int m0 = blockIdx.x * 64;

  const int ar = tid >> 4, ac = tid & 15;

  f32x4 rA[2];
  f32x4 rB[8];

  auto gload = [&](int t) {
    const int k0 = t * BK;
#pragma unroll
    for (int p = 0; p < 2; ++p)
      rA[p] = *reinterpret_cast<const f32x4*>(
          seq + (size_t)(m0 + ar + p * 32) * FT + k0 + ac * 4);
#pragma unroll
    for (int p = 0; p < 8; ++p)
      rB[p] = *reinterpret_cast<const f32x4*>(
          W + (size_t)(ar + p * 32) * FT + k0 + ac * 4);
  };
  auto lwrite = [&](int buf) {
    char* lAp = (char*)lA[buf];
    char* lBp = (char*)lB[buf];
#pragma unroll
    for (int p = 0; p < 2; ++p) {
      ushort4 u = make_ushort4(f2bf(rA[p][0]), f2bf(rA[p][1]), f2bf(rA[p][2]), f2bf(rA[p][3]));
      *reinterpret_cast<ushort4*>(lAp + swz(ar + p * 32, ac * 8)) = u;
    }
#pragma unroll
    for (int p = 0; p < 8; ++p) {
      ushort4 u = make_ushort4(f2bf(rB[p][0]), f2bf(rB[p][1]), f2bf(rB[p][2]), f2bf(rB[p][3]));
      *reinterpret_cast<ushort4*>(lBp + swz(ar + p * 32, ac * 8)) = u;
    }
  };

  f32x4 acc[2][4];
  const f32x4 zero = {0.f, 0.f, 0.f, 0.f};
#pragma unroll
  for (int mi = 0; mi < 2; ++mi)
#pragma unroll
    for (int ni = 0; ni < 4; ++ni) acc[mi][ni] = zero;

  gload(0);
  lwrite(0);
  const int NTA = FT / BK;  // 4
  for (int t = 0; t < NTA; ++t) {
    const int cur = t & 1;
    __syncthreads();
    if (t + 1 < NTA) gload(t + 1);
    mma_step((const char*)lA[cur], (const char*)lB[cur], lane, wm, wn, acc);
    if (t + 1 < NTA) lwrite(cur ^ 1);
  }

#pragma unroll
  for (int mi = 0; mi < 2; ++mi) {
    const int grow = m0 + wm * 32 + mi * 16 + ((lane >> 4) << 2);
    const int batch = grow >> 12;
    const int n = grow & (NSEQ - 1);
#pragma unroll
    for (int ni = 0; ni < 4; ++ni) {
      const int o = wn * 64 + ni * 16 + (lane & 15);
      const float bo = bias[o];
      ushort4 u;
      u.x = f2bf(acc[mi][ni][0] + bo);
      u.y = f2bf(acc[mi][ni][1] + bo);
      u.z = f2bf(acc[mi][ni][2] + bo);
      u.w = f2bf(acc[mi][ni][3] + bo);
      *reinterpret_cast<ushort4*>(hT + (size_t)(batch * FT + o) * NSEQ + n) = u;
    }
  }
}

// ---------------- Kernel B: out = PReLU(adj @ h), barrier-free ----------------
// BM=64, BN=256, BK=64, grid 256, 512 thr (8 waves 2x4). NO LDS staging, NO
// barriers in the main loop: each wave gathers its own MFMA fragments directly
// from global (A: 8 consecutive fp32/lane from adj, cvt in-reg; B: 8
// consecutive bf16/lane from hT). 2-set software pipeline; waves slip freely,
// co-resident waves hide each other's latency. LDS only for the epilogue.
__global__ __launch_bounds__(512, 2) void bmm_prelu_kernel(
    const float* __restrict__ adj, const ushort* __restrict__ hT,
    const float* __restrict__ alphaP, float* __restrict__ out) {
  __shared__ __align__(16) float lo[64 * 264];  // epilogue only (67.6 KB)

  const int tid = threadIdx.x;
  const int lane = tid & 63;
  const int wid = tid >> 6;
  const int wm = wid >> 2, wn = wid & 3;

  // XCD-contiguous remap (bijective: 256 = 8 * 32); pins each batch's hT
  // slice (2 MB) into two XCDs' L2.
  const int bid = blockIdx.x;
  const int sbid = (bid & 7) * 32 + (bid >> 3);
  const int batch = sbid >> 6;
  const int m0 = (sbid & 63) * 64;

  const int r16 = lane & 15, g8 = (lane >> 4) * 8;
  const float* aBase =
      adj + ((size_t)batch * NSEQ + m0 + wm * 32 + r16) * NSEQ + g8;
  const ushort* bBase =
      hT + ((size_t)batch * FT + wn * 64 + r16) * NSEQ + g8;

  typedef f32x4 ASet[2][2][2];  // [mi][kk][p]
  typedef bf16x8 BSet[4][2];    // [ni][kk]
  ASet A0, A1;
  BSet B0, B1;

  f32x4 acc[2][4];
  const f32x4 zero = {0.f, 0.f, 0.f, 0.f};
#pragma unroll
  for (int mi = 0; mi < 2; ++mi)
#pragma unroll
    for (int ni = 0; ni < 4; ++ni) acc[mi][ni] = zero;

  auto load_set = [&](int t, ASet& A, BSet& B) {
    const int k0 = t * BK;
#pragma unroll
    for (int mi = 0; mi < 2; ++mi)
#pragma unroll
      for (int kk = 0; kk < 2; ++kk)
#pragma unroll
        for (int p = 0; p < 2; ++p)
          A[mi][kk][p] = *reinterpret_cast<const f32x4*>(
              aBase + (size_t)mi * 16 * NSEQ + k0 + kk * 32 + p * 4);
#pragma unroll
    for (int ni = 0; ni < 4; ++ni)
#pragma unroll
      for (int kk = 0; kk < 2; ++kk)
        B[ni][kk] = *reinterpret_cast<const bf16x8*>(
            bBase + (size_t)ni * 16 * NSEQ + k0 + kk * 32);
  };

  auto compute = [&](ASet& A, BSet& B) {
#pragma unroll
    for (int kk = 0; kk < 2; ++kk) {
      bf16x8 a[2];
#pragma unroll
      for (int mi = 0; mi < 2; ++mi)
#pragma unroll
        for (int p = 0; p < 2; ++p)
#pragma unroll
          for (int e = 0; e < 4; ++e)
            a[mi][p * 4 + e] = (short)f2bf(A[mi][kk][p][e]);
#pragma unroll
      for (int mi = 0; mi < 2; ++mi)
#pragma unroll
        for (int ni = 0; ni < 4; ++ni)
          acc[mi][ni] = __builtin_amdgcn_mfma_f32_16x16x32_bf16(
              a[mi], B[ni][kk], acc[mi][ni], 0, 0, 0);
    }
  };

  // 2-set software pipeline over 64 K-steps, no barriers anywhere.
  load_set(0, A0, B0);
  for (int j = 0; j < 31; ++j) {
    load_set(2 * j + 1, A1, B1);
    compute(A0, B0);
    load_set(2 * j + 2, A0, B0);
    compute(A1, B1);
  }
  load_set(63, A1, B1);
  compute(A0, B0);
  compute(A1, B1);

  // Epilogue: PReLU -> LDS (padded pitch) -> coalesced nontemporal rows.
  const float alpha = *alphaP;
  const int PITCH = 264;
#pragma unroll
  for (int mi = 0; mi < 2; ++mi) {
    const int rbase = wm * 32 + mi * 16 + ((lane >> 4) << 2);
#pragma unroll
    for (int ni = 0; ni < 4; ++ni) {
      const int o = wn * 64 + ni * 16 + (lane & 15);
#pragma unroll
      for (int j = 0; j < 4; ++j) {
        float v = acc[mi][ni][j];
        v = v > 0.f ? v : alpha * v;
        lo[(rbase + j) * PITCH + o] = v;
      }
    }
  }
  __syncthreads();
  float* outB = out + ((size_t)batch * NSEQ + m0) * FT;
  const int r = tid >> 3, c8 = tid & 7;
#pragma unroll
  for (int k = 0; k < 8; ++k) {
    const int g = c8 + k * 8;
    f32x4 v = *reinterpret_cast<const f32x4*>(lo + r * PITCH + g * 4);
    __builtin_nontemporal_store(v, reinterpret_cast<f32x4*>(outB + (size_t)r * FT + g * 4));
  }
}

extern "C" void kernel_launch(void* const* d_in, const int* in_sizes, int n_in,
                              void* d_out, int out_size, void* d_ws, size_t ws_size,
                              hipStream_t stream) {
  const float* seq = (const float*)d_in[0];
  const float* adj = (const float*)d_in[1];
  const float* W = (const float*)d_in[2];
  const float* bias = (const float*)d_in[3];
  const float* alpha = (const float*)d_in[4];
  float* out = (float*)d_out;
  ushort* hT = (ushort*)d_ws;  // [4][256][4096] bf16 = 8 MB

  linear_kernel<<<256, 512, 0, stream>>>(seq, W, bias, hT);
  bmm_prelu_kernel<<<256, 512, 0, stream>>>(adj, hT, alpha, out);
}

// Round 7
// 90.513 us; speedup vs baseline: 2.7119x; 2.7119x over previous
//
#include <hip/hip_runtime.h>
#include <hip/hip_bf16.h>

#define NSEQ 4096
#define FT 256
#define BK 64
#define NT (NSEQ / BK)  // 64

typedef __attribute__((ext_vector_type(8))) short bf16x8;
typedef __attribute__((ext_vector_type(4))) float f32x4;

__device__ __forceinline__ ushort f2bf(float f) {
  __hip_bfloat16 h = __float2bfloat16(f);
  return *reinterpret_cast<const ushort*>(&h);
}

// XOR swizzle of 16B granules within a 128B row.
__device__ __forceinline__ int swz(int row, int byteInRow) {
  return row * 128 + (byteInRow ^ ((row & 7) << 4));
}

// One BK=64 K-step: 12 ds_read_b128 + 16 MFMA per wave.
__device__ __forceinline__ void mma_step(const char* lAp, const char* lBp,
                                         int lane, int wm, int wn,
                                         f32x4 acc[2][4]) {
  const int r16 = lane & 15;
  const int g16 = (lane >> 4) * 16;
#pragma unroll
  for (int kk = 0; kk < 2; ++kk) {
    const int kb = kk * 64 + g16;
    bf16x8 a[2], b[4];
#pragma unroll
    for (int mi = 0; mi < 2; ++mi) {
      const int row = wm * 32 + mi * 16 + r16;
      a[mi] = *reinterpret_cast<const bf16x8*>(lAp + swz(row, kb));
    }
#pragma unroll
    for (int ni = 0; ni < 4; ++ni) {
      const int row = wn * 64 + ni * 16 + r16;
      b[ni] = *reinterpret_cast<const bf16x8*>(lBp + swz(row, kb));
    }
#pragma unroll
    for (int mi = 0; mi < 2; ++mi)
#pragma unroll
      for (int ni = 0; ni < 4; ++ni)
        acc[mi][ni] = __builtin_amdgcn_mfma_f32_16x16x32_bf16(a[mi], b[ni],
                                                             acc[mi][ni], 0, 0, 0);
  }
}

// ---------------- Kernel A: hT[b][o][n] = (seq @ W^T + b) as bf16 ----------------
__global__ __launch_bounds__(512) void linear_kernel(
    const float* __restrict__ seq, const float* __restrict__ W,
    const float* __restrict__ bias, ushort* __restrict__ hT) {
  __shared__ __align__(16) ushort lA[2][64 * 64];
  __shared__ __align__(16) ushort lB[2][256 * 64];

  const int tid = threadIdx.x;
  const int lane = tid & 63;
  const int wid = tid >> 6;
  const int wm = wid >> 2, wn = wid & 3;
  const int m0 = blockIdx.x * 64;

  const int ar = tid >> 4, ac = tid & 15;

  f32x4 rA[2];
  f32x4 rB[8];

  auto gload = [&](int t) {
    const int k0 = t * BK;
#pragma unroll
    for (int p = 0; p < 2; ++p)
      rA[p] = *reinterpret_cast<const f32x4*>(
          seq + (size_t)(m0 + ar + p * 32) * FT + k0 + ac * 4);
#pragma unroll
    for (int p = 0; p < 8; ++p)
      rB[p] = *reinterpret_cast<const f32x4*>(
          W + (size_t)(ar + p * 32) * FT + k0 + ac * 4);
  };
  auto lwrite = [&](int buf) {
    char* lAp = (char*)lA[buf];
    char* lBp = (char*)lB[buf];
#pragma unroll
    for (int p = 0; p < 2; ++p) {
      ushort4 u = make_ushort4(f2bf(rA[p][0]), f2bf(rA[p][1]), f2bf(rA[p][2]), f2bf(rA[p][3]));
      *reinterpret_cast<ushort4*>(lAp + swz(ar + p * 32, ac * 8)) = u;
    }
#pragma unroll
    for (int p = 0; p < 8; ++p) {
      ushort4 u = make_ushort4(f2bf(rB[p][0]), f2bf(rB[p][1]), f2bf(rB[p][2]), f2bf(rB[p][3]));
      *reinterpret_cast<ushort4*>(lBp + swz(ar + p * 32, ac * 8)) = u;
    }
  };

  f32x4 acc[2][4];
  const f32x4 zero = {0.f, 0.f, 0.f, 0.f};
#pragma unroll
  for (int mi = 0; mi < 2; ++mi)
#pragma unroll
    for (int ni = 0; ni < 4; ++ni) acc[mi][ni] = zero;

  gload(0);
  lwrite(0);
  const int NTA = FT / BK;  // 4
  for (int t = 0; t < NTA; ++t) {
    const int cur = t & 1;
    __syncthreads();
    if (t + 1 < NTA) gload(t + 1);
    mma_step((const char*)lA[cur], (const char*)lB[cur], lane, wm, wn, acc);
    if (t + 1 < NTA) lwrite(cur ^ 1);
  }

#pragma unroll
  for (int mi = 0; mi < 2; ++mi) {
    const int grow = m0 + wm * 32 + mi * 16 + ((lane >> 4) << 2);
    const int batch = grow >> 12;
    const int n = grow & (NSEQ - 1);
#pragma unroll
    for (int ni = 0; ni < 4; ++ni) {
      const int o = wn * 64 + ni * 16 + (lane & 15);
      const float bo = bias[o];
      ushort4 u;
      u.x = f2bf(acc[mi][ni][0] + bo);
      u.y = f2bf(acc[mi][ni][1] + bo);
      u.z = f2bf(acc[mi][ni][2] + bo);
      u.w = f2bf(acc[mi][ni][3] + bo);
      *reinterpret_cast<ushort4*>(hT + (size_t)(batch * FT + o) * NSEQ + n) = u;
    }
  }
}

// ---------------- Kernel B: out = PReLU(adj @ h), deep-pipelined ----------------
// BM=64, BN=256 (adj read once), BK=64. 512 thr (8 waves 2x4), grid 256.
// hT: global_load_lds, 4 LDS buffers, 3-deep. adj: PLAIN loads (L3-retained
// across replays), 4 reg-sets, 3-deep. One counted vmcnt(12)/iter, never 0
// until the tail. s_setprio(1) around the MFMA cluster (T5).
__global__ __launch_bounds__(512) void bmm_prelu_kernel(
    const float* __restrict__ adj, const ushort* __restrict__ hT,
    const float* __restrict__ alphaP, float* __restrict__ out) {
  __shared__ __align__(16) ushort lA[2][64 * 64];   // 16 KB
  __shared__ __align__(16) ushort lB[4][256 * 64];  // 128 KB

  const int tid = threadIdx.x;
  const int lane = tid & 63;
  const int wid = tid >> 6;
  const int wm = wid >> 2, wn = wid & 3;

  // XCD-contiguous remap (bijective: 256 = 8 * 32).
  const int bid = blockIdx.x;
  const int sbid = (bid & 7) * 32 + (bid >> 3);
  const int batch = sbid >> 6;
  const int m0 = (sbid & 63) * 64;

  const float* adjB = adj + (size_t)batch * NSEQ * NSEQ + (size_t)m0 * NSEQ;
  const ushort* hTB = hT + (size_t)batch * FT * NSEQ;

  const int ar = tid >> 4, ac = tid & 15;      // adj staging geometry
  const int brow = wid * 8 + (lane >> 3);      // hT row (+ p*64)
  const int bg = (lane & 7) ^ (lane >> 3);     // pre-swizzled source granule

  f32x4 rA0[2], rA1[2], rA2[2], rA3[2];

  f32x4 acc[2][4];
  const f32x4 zero = {0.f, 0.f, 0.f, 0.f};
#pragma unroll
  for (int mi = 0; mi < 2; ++mi)
#pragma unroll
    for (int ni = 0; ni < 4; ++ni) acc[mi][ni] = zero;

  auto issueA = [&](int t, f32x4* r) {
    const int k0 = t * BK;
#pragma unroll
    for (int p = 0; p < 2; ++p)
      r[p] = *reinterpret_cast<const f32x4*>(
          adjB + (size_t)(ar + p * 32) * NSEQ + k0 + ac * 4);
  };
  auto issueB = [&](int t, int ib) {
    const int k0 = t * BK;
#pragma unroll
    for (int p = 0; p < 4; ++p) {
      const ushort* gp = hTB + (size_t)(p * 64 + brow) * NSEQ + k0 + bg * 8;
      ushort* lp = &lB[ib][p * 4096 + wid * 512];
      __builtin_amdgcn_global_load_lds(
          (const __attribute__((address_space(1))) void*)gp,
          (__attribute__((address_space(3))) void*)lp, 16, 0, 0);
    }
  };
  auto writeA = [&](const f32x4* r, int ia) {
    char* lAp = (char*)lA[ia];
#pragma unroll
    for (int p = 0; p < 2; ++p) {
      ushort4 u = make_ushort4(f2bf(r[p][0]), f2bf(r[p][1]), f2bf(r[p][2]), f2bf(r[p][3]));
      *reinterpret_cast<ushort4*>(lAp + swz(ar + p * 32, ac * 8)) = u;
    }
  };

  // Prologue. Queue (oldest->newest): A0(2) B0(4) A1(2) B1(4) A2(2) B2(4)=18.
  issueA(0, rA0);
  issueB(0, 0);
  issueA(1, rA1);
  issueB(1, 1);
  issueA(2, rA2);
  issueB(2, 2);
  asm volatile("s_waitcnt vmcnt(16)" ::: "memory");  // A0 regs ready
  writeA(rA0, 0);
  asm volatile("s_waitcnt vmcnt(12) lgkmcnt(0)" ::: "memory");  // B0 in LDS
  __builtin_amdgcn_s_barrier();
  __builtin_amdgcn_sched_barrier(0);

  // body(t): issue A(t+3)->rA[(t+3)&3], B(t+3)->lB[(t+3)&3];
  //          mma on lA[t&1], lB[t&3] (setprio-wrapped);
  //          vmcnt(12) drains exactly A(t+1)+B(t+1);
  //          writeA rA[(t+1)&3] -> lA[(t+1)&1]; lgkm0; barrier.
  // Steady-state invariant after the wait: 12 outstanding (2 tiles + issue).
  auto body = [&](int t, f32x4* rIss, const f32x4* rWr,
                  int ibIss, int ibRd, int iaRd, int iaWr) {
    issueA(t + 3, rIss);
    issueB(t + 3, ibIss);
    __builtin_amdgcn_s_setprio(1);
    mma_step((const char*)lA[iaRd], (const char*)lB[ibRd], lane, wm, wn, acc);
    __builtin_amdgcn_s_setprio(0);
    asm volatile("s_waitcnt vmcnt(12)" ::: "memory");
    writeA(rWr, iaWr);
    asm volatile("s_waitcnt lgkmcnt(0)" ::: "memory");
    __builtin_amdgcn_s_barrier();
    __builtin_amdgcn_sched_barrier(0);
  };

  // t = 0..59 (period-4 static parity), then t = 60, then tail.
  for (int j = 0; j < 15; ++j) {
    body(j * 4 + 0, rA3, rA1, 3, 0, 0, 1);
    body(j * 4 + 1, rA0, rA2, 0, 1, 1, 0);
    body(j * 4 + 2, rA1, rA3, 1, 2, 0, 1);
    body(j * 4 + 3, rA2, rA0, 2, 3, 1, 0);
  }
  body(60, rA3, rA1, 3, 0, 0, 1);
  {  // t = 61: no issue. Outstanding: A62(2) B62(4) A63(2) B63(4) = 12.
    __builtin_amdgcn_s_setprio(1);
    mma_step((const char*)lA[1], (const char*)lB[1], lane, wm, wn, acc);
    __builtin_amdgcn_s_setprio(0);
    asm volatile("s_waitcnt vmcnt(6)" ::: "memory");  // A62+B62 done
    writeA(rA2, 0);
    asm volatile("s_waitcnt lgkmcnt(0)" ::: "memory");
    __builtin_amdgcn_s_barrier();
    __builtin_amdgcn_sched_barrier(0);
  }
  {  // t = 62
    __builtin_amdgcn_s_setprio(1);
    mma_step((const char*)lA[0], (const char*)lB[2], lane, wm, wn, acc);
    __builtin_amdgcn_s_setprio(0);
    asm volatile("s_waitcnt vmcnt(0)" ::: "memory");  // A63+B63 done
    writeA(rA3, 1);
    asm volatile("s_waitcnt lgkmcnt(0)" ::: "memory");
    __builtin_amdgcn_s_barrier();
    __builtin_amdgcn_sched_barrier(0);
  }
  // t = 63
  mma_step((const char*)lA[1], (const char*)lB[3], lane, wm, wn, acc);

  // Epilogue: PReLU -> LDS (overlay on lB, padded pitch) -> coalesced rows.
  const float alpha = *alphaP;
  __syncthreads();
  float* lo = (float*)&lB[0][0];  // 64 x 264 f32 = 66 KB (fits in 128 KB lB)
  const int PITCH = 264;
#pragma unroll
  for (int mi = 0; mi < 2; ++mi) {
    const int rbase = wm * 32 + mi * 16 + ((lane >> 4) << 2);
#pragma unroll
    for (int ni = 0; ni < 4; ++ni) {
      const int o = wn * 64 + ni * 16 + (lane & 15);
#pragma unroll
      for (int j = 0; j < 4; ++j) {
        float v = acc[mi][ni][j];
        v = v > 0.f ? v : alpha * v;
        lo[(rbase + j) * PITCH + o] = v;
      }
    }
  }
  __syncthreads();
  float* outB = out + ((size_t)batch * NSEQ + m0) * FT;
  const int r = tid >> 3, c8 = tid & 7;
#pragma unroll
  for (int k = 0; k < 8; ++k) {
    const int g = c8 + k * 8;
    f32x4 v = *reinterpret_cast<const f32x4*>(lo + r * PITCH + g * 4);
    __builtin_nontemporal_store(v, reinterpret_cast<f32x4*>(outB + (size_t)r * FT + g * 4));
  }
}

extern "C" void kernel_launch(void* const* d_in, const int* in_sizes, int n_in,
                              void* d_out, int out_size, void* d_ws, size_t ws_size,
                              hipStream_t stream) {
  const float* seq = (const float*)d_in[0];
  const float* adj = (const float*)d_in[1];
  const float* W = (const float*)d_in[2];
  const float* bias = (const float*)d_in[3];
  const float* alpha = (const float*)d_in[4];
  float* out = (float*)d_out;
  ushort* hT = (ushort*)d_ws;  // [4][256][4096] bf16 = 8 MB

  linear_kernel<<<256, 512, 0, stream>>>(seq, W, bias, hT);
  bmm_prelu_kernel<<<256, 512, 0, stream>>>(adj, hT, alpha, out);
}